// Round 9
// baseline (494.938 us; speedup 1.0000x reference)
//
#include <hip/hip_runtime.h>
#include <hip/hip_bf16.h>

#define NN 100000
#define NE 1000000
#define NR 8

// binned counting sort params
#define EB 1024
#define NBLK 977          // ceil(NE/EB)
#define NBUCK 196         // dst>>9 buckets
#define NT (NBUCK*NBLK)   // 191492 histogram cells
#define NBB 749           // ceil(NT/256)

#define K3DPB 32          // dsts per block in k3
#define K3CAP 160         // staged edges per wave (8 dsts, mean 80, sd ~9)

// fused pre-kernel block ranges
#define K0_BLKS  160      // NR*5120/256
#define PRE_BLKS (K0_BLKS + NBLK)

// k_mid: sort group (blockIdx 0..NSORT-1, whole chain w/ device barriers)
//        + full unsliced k1 (blockIdx NSORT..NSORT+K1CH-1)
#define NSORT NBLK        // 977
#define K1CH  1563

typedef unsigned short u16;
typedef unsigned int u32;
typedef __attribute__((ext_vector_type(8))) short bf16x8;
typedef __attribute__((ext_vector_type(4))) float f32x4;

static __device__ __forceinline__ float bf2f(u16 u) {
    union { u32 i; float f; } v; v.i = ((u32)u) << 16; return v.f;
}
static __device__ __forceinline__ float bflo(u32 u) {
    union { u32 i; float f; } v; v.i = u << 16; return v.f;
}
static __device__ __forceinline__ float bfhi(u32 u) {
    union { u32 i; float f; } v; v.i = u & 0xffff0000u; return v.f;
}
static __device__ __forceinline__ u16 f2bf(float f) {
    __hip_bfloat16 h = __float2bfloat16(f);
    return *reinterpret_cast<u16*>(&h);
}
static __device__ __forceinline__ float ldf(const void* p, int idx, int isf32) {
    return isf32 ? ((const float*)p)[idx] : bf2f(((const u16*)p)[idx]);
}

// device-scope barrier among the NSORT sort blocks only. k1 blocks never
// wait -> no circular residency wait -> deadlock-free for any dispatch
// order (sort blocks <= residency capacity; all other blocks terminate).
static __device__ __forceinline__ void gbar(int* cnt, int target)
{
    __syncthreads();
    if (threadIdx.x == 0) {
        __threadfence();                                   // release prior writes
        atomicAdd(cnt, 1);                                 // device-scope RMW
        while (__hip_atomic_load(cnt, __ATOMIC_RELAXED,
                                 __HIP_MEMORY_SCOPE_AGENT) < target)
            __builtin_amdgcn_s_sleep(32);
        __threadfence();                                   // acquire: drop stale lines
    }
    __syncthreads();
}

// detect helper: one wave scans first 512 u16 words of x; >50 insane => fp32
static __device__ __forceinline__ int detect_wave(const u16* xw, int lane)
{
    int insane = 0;
    for (int k = lane; k < 512; k += 64) {
        u16 w = xw[k];
        int ex = (w >> 7) & 0xFF;
        bool sane = ((w & 0x7FFF) == 0) || (ex >= 96 && ex <= 159);
        insane += sane ? 0 : 1;
    }
    for (int off = 32; off; off >>= 1) insane += __shfl_down(insane, off);
    return insane;   // valid in lane 0
}

// --------------------------------------------------------------------------
// k_pre: fused {k0_prep | binA} + zeroes the sort-barrier counters.
// --------------------------------------------------------------------------
__global__ __launch_bounds__(256) void k_pre(
    const void* __restrict__ xin, int* __restrict__ flag,
    const void* __restrict__ cw, const void* __restrict__ al,
    const void* __restrict__ ar, u16* __restrict__ Bpre,
    const int* __restrict__ dsti, int* __restrict__ histT,
    int* __restrict__ sortcnt)
{
    __shared__ int sflag;
    __shared__ int hist[NBUCK];
    int t = threadIdx.x;
    int b = blockIdx.x;

    if (b == 0 && t < 4) sortcnt[t] = 0;

    if (b < K0_BLKS) {
        if (t < 64) {
            int insane = detect_wave((const u16*)xin, t);
            if (t == 0) {
                sflag = (insane > 50) ? 1 : 0;
                if (b == 0) *flag = sflag;
            }
        }
        __syncthreads();
        int isf32 = sflag;
        int tid = b * 256 + t;
        if (tid >= NR * 5120) return;
        int r = tid / 5120, rem = tid % 5120;
        int c = rem >> 3, j = rem & 7;
        int nt = c >> 7, kk = (c >> 6) & 1, lc = c & 63;
        int i = kk * 32 + ((lc >> 4) << 3) + j;
        int d = lc & 15;
        u16 val;
        if (nt < 4) {
            val = f2bf(ldf(cw, ((r * 4 + nt) * 64 + i) * 16 + d, isf32));
        } else if (d < 8) {
            int h = d >> 1;
            const void* attn = (d & 1) ? ar : al;
            float s = 0.f;
            for (int dd = 0; dd < 16; ++dd)
                s += ldf(cw, ((r * 4 + h) * 64 + i) * 16 + dd, isf32)
                   * ldf(attn, (r * 4 + h) * 16 + dd, isf32);
            val = f2bf(s);
        } else {
            val = 0;
        }
        Bpre[tid] = val;
    } else {
        int blk = b - K0_BLKS;
        if (t < NBUCK) hist[t] = 0;
        __syncthreads();
        int base = blk * EB;
        for (int j = 0; j < EB; j += 256) {
            int e = base + j + t;
            if (e < NE) atomicAdd(&hist[dsti[e] >> 9], 1);
        }
        __syncthreads();
        if (t < NBUCK) histT[t * NBLK + blk] = hist[t];
    }
}

// --------------------------------------------------------------------------
// k1 body (v8, verified: 47us, 0 conflicts, FETCH 13MB, WRITE 125MB).
// --------------------------------------------------------------------------
static __device__ __forceinline__ void k1_body(
    int cb, unsigned char* smem,
    const void* __restrict__ xin, const u16* __restrict__ Bpre,
    u16* __restrict__ feat_all, float* __restrict__ el_all, float* __restrict__ er_all)
{
    u32 (*ldsT)[64][32] = (u32 (*)[64][32])smem;   // [2][64][32] = 16KB
    int n0 = cb * 64;
    int tid = threadIdx.x;
    int wave = tid >> 6, lane = tid & 63;
    int col = lane & 15, quad = lane >> 4;

    int insane = detect_wave((const u16*)xin, lane);
    insane = __shfl(insane, 0);
    int isf32 = (insane > 50) ? 1 : 0;

    int node = n0 + wave * 16 + col;
    int nclamp = node < NN ? node : NN - 1;
    bool nvalid = node < NN;

    bf16x8 afrag0, afrag1;
    if (!isf32) {
        const u16* xb = (const u16*)xin + nclamp * 64 + quad * 8;
        afrag0 = *(const bf16x8*)&xb[0];
        afrag1 = *(const bf16x8*)&xb[32];
    } else {
        const float* xf = (const float*)xin + nclamp * 64 + quad * 8;
#pragma unroll
        for (int j = 0; j < 8; ++j) {
            afrag0[j] = (short)f2bf(xf[j]);
            afrag1[j] = (short)f2bf(xf[32 + j]);
        }
    }

#pragma unroll 1
    for (int ch = 0; ch < 4; ++ch) {
#pragma unroll
        for (int rr = 0; rr < 2; ++rr) {
            int r = ch * 2 + rr;
            f32x4 acc[5];
#pragma unroll
            for (int nt = 0; nt < 5; ++nt) acc[nt] = f32x4{0.f, 0.f, 0.f, 0.f};
#pragma unroll
            for (int nt = 0; nt < 5; ++nt) {
                bf16x8 b0 = *(const bf16x8*)&Bpre[r * 5120 + ((nt * 2 + 0) * 64 + lane) * 8];
                bf16x8 b1 = *(const bf16x8*)&Bpre[r * 5120 + ((nt * 2 + 1) * 64 + lane) * 8];
                acc[nt] = __builtin_amdgcn_mfma_f32_16x16x32_bf16(b0, afrag0, acc[nt], 0, 0, 0);
                acc[nt] = __builtin_amdgcn_mfma_f32_16x16x32_bf16(b1, afrag1, acc[nt], 0, 0, 0);
            }
#pragma unroll
            for (int nt = 0; nt < 4; ++nt) {
                u32 lo = (u32)f2bf(acc[nt][0]) | ((u32)f2bf(acc[nt][1]) << 16);
                u32 hi = (u32)f2bf(acc[nt][2]) | ((u32)f2bf(acc[nt][3]) << 16);
                int w = (nt * 8 + quad * 2) ^ (col * 2);
                *(uint2*)&ldsT[rr][wave * 16 + col][w] = uint2{lo, hi};
            }
            if (nvalid && quad < 2) {
                int eb = (r * NN + node) * 4 + quad * 2;
                *(float2*)&el_all[eb] = float2{acc[4][0], acc[4][2]};
                *(float2*)&er_all[eb] = float2{acc[4][1], acc[4][3]};
            }
        }
        __syncthreads();
#pragma unroll
        for (int it = 0; it < 8; ++it) {
            int u = it * 256 + tid;
            int rr = u >> 10;
            int v = u & 1023;
            int nl = v >> 4;
            int p  = v & 15;
            int w  = (p * 2) ^ ((nl & 15) * 2);
            uint2 val = *(const uint2*)&ldsT[rr][nl][w];
            int nd = n0 + nl;
            if (nd < NN)
                *(uint2*)&feat_all[((ch * 2 + rr) * NN + nd) * 64 + p * 4] = val;
        }
        __syncthreads();
    }
}

// --------------------------------------------------------------------------
// Sort-stage bodies (256 threads; all verified correct in round 8).
// --------------------------------------------------------------------------
static __device__ __forceinline__ void scanB1_body(
    int b, unsigned char* smem, int* __restrict__ histT, int* __restrict__ bsum)
{
    int* wtot = (int*)smem;
    int t = threadIdx.x;
    int gi = b * 256 + t;
    int v = (gi < NT) ? histT[gi] : 0;
    int lane = t & 63, w = t >> 6;
    int s = v;
#pragma unroll
    for (int m = 1; m < 64; m <<= 1) {
        int u = __shfl_up(s, m);
        if (lane >= m) s += u;
    }
    if (lane == 63) wtot[w] = s;
    __syncthreads();
    int wb = 0;
    for (int i = 0; i < w; ++i) wb += wtot[i];
    if (gi < NT) histT[gi] = wb + s - v;
    if (t == 255) bsum[b] = wb + s;
}

static __device__ __forceinline__ void scanB2_body(
    unsigned char* smem, const int* __restrict__ bsum, int* __restrict__ boff,
    const int* __restrict__ histT, int* __restrict__ bstart)
{
    int* wtot  = (int*)smem;                  // 4
    int* sboff = (int*)(smem + 16);           // NBB
    int* carry = (int*)(smem + 16 + 4 * NBB);
    int t = threadIdx.x;
    if (t == 0) *carry = 0;
    __syncthreads();
    for (int c = 0; c < 3; ++c) {             // 3*256 >= NBB
        int idx = c * 256 + t;
        int v = (idx < NBB) ? bsum[idx] : 0;
        int lane = t & 63, w = t >> 6;
        int s = v;
#pragma unroll
        for (int m = 1; m < 64; m <<= 1) {
            int u = __shfl_up(s, m);
            if (lane >= m) s += u;
        }
        if (lane == 63) wtot[w] = s;
        __syncthreads();
        int wb = 0;
        for (int i = 0; i < w; ++i) wb += wtot[i];
        int ex = *carry + wb + s - v;
        if (idx < NBB) sboff[idx] = ex;
        __syncthreads();
        if (t == 255) *carry += wb + s;
        __syncthreads();
    }
    for (int i = t; i < NBB; i += 256) boff[i] = sboff[i];
    if (t < NBUCK) {
        int gi = t * NBLK;
        bstart[t] = histT[gi] + sboff[gi >> 8];
    }
    if (t == 0) bstart[NBUCK] = NE;
}

static __device__ __forceinline__ void binC_body(
    int b, unsigned char* smem,
    const int* __restrict__ srci, const int* __restrict__ dsti,
    const int* __restrict__ reli, const int* __restrict__ histT,
    const int* __restrict__ boff, int* __restrict__ key_b)
{
    int* cur = (int*)smem;                    // NBUCK
    int t = threadIdx.x;
    if (t < NBUCK) {
        int gi = t * NBLK + b;
        cur[t] = histT[gi] + boff[gi >> 8];
    }
    __syncthreads();
    int base = b * EB;
    for (int j = 0; j < EB; j += 256) {
        int e = base + j + t;
        if (e < NE) {
            int d = dsti[e];
            int key = ((d & 511) << 20) | (reli[e] << 17) | srci[e];
            int pos = atomicAdd(&cur[d >> 9], 1);
            key_b[pos] = key;
        }
    }
}

static __device__ __forceinline__ void binD_body(
    int b, unsigned char* smem,
    const int* __restrict__ bstart, const int* __restrict__ key_b,
    int* __restrict__ key_s, int* __restrict__ off)
{
    int* cnt   = (int*)smem;                  // 512
    int* wtot  = (int*)(smem + 2048);         // 4
    int* carry = (int*)(smem + 2064);
    int t = threadIdx.x;
    int s0 = bstart[b], s1 = bstart[b + 1];
    cnt[t] = 0; cnt[t + 256] = 0;
    if (t == 0) *carry = 0;
    __syncthreads();
    for (int j = s0 + t; j < s1; j += 256)
        atomicAdd(&cnt[(key_b[j] >> 20) & 511], 1);
    __syncthreads();
    int excl[2];
#pragma unroll
    for (int c = 0; c < 2; ++c) {
        int v = cnt[c * 256 + t];
        int lane = t & 63, w = t >> 6;
        int s = v;
#pragma unroll
        for (int m = 1; m < 64; m <<= 1) {
            int u = __shfl_up(s, m);
            if (lane >= m) s += u;
        }
        if (lane == 63) wtot[w] = s;
        __syncthreads();
        int wb = 0;
        for (int i = 0; i < w; ++i) wb += wtot[i];
        excl[c] = s0 + *carry + wb + s - v;
        __syncthreads();
        if (t == 255) *carry += wb + s;
        __syncthreads();
    }
#pragma unroll
    for (int c = 0; c < 2; ++c) {
        int d = (b << 9) + c * 256 + t;
        if (d < NN) off[d] = excl[c];
    }
    cnt[t] = excl[0]; cnt[t + 256] = excl[1];
    if (b == 0 && t == 0) off[NN] = NE;
    __syncthreads();
    for (int j = s0 + t; j < s1; j += 256) {
        int key = key_b[j];
        int pos = atomicAdd(&cnt[(key >> 20) & 511], 1);
        key_s[pos] = key;
    }
}

// --------------------------------------------------------------------------
// k_mid: ONE launch = {977 sort blocks running the whole chain with device
// barriers} ∥ {full 1563-block k1, UNSLICED}. Round-8 lesson: slicing k1
// into 390-block launches collapsed its occupancy (1.5 blk/CU) and cost
// more than the hidden sort saved. Here k1 keeps full parallelism; the
// ~26us sort chain hides under k1's ~47us. Sort blocks take low blockIdx
// so they're resident first; k1 blocks never wait on anything, so any
// dispatch order is deadlock-free (degrades only perf).
// --------------------------------------------------------------------------
__global__ __launch_bounds__(256) void k_mid(
    const void* __restrict__ xin, const u16* __restrict__ Bpre,
    u16* __restrict__ feat_all, float* __restrict__ el_all, float* __restrict__ er_all,
    const int* __restrict__ srci, const int* __restrict__ dsti,
    const int* __restrict__ reli,
    int* __restrict__ histT, int* __restrict__ bsum, int* __restrict__ boff,
    int* __restrict__ bstart, int* __restrict__ key_b, int* __restrict__ key_s,
    int* __restrict__ off, int* __restrict__ sortcnt)
{
    __shared__ alignas(16) unsigned char smem[16448];
    int b = blockIdx.x;
    if (b >= NSORT) {
        k1_body(b - NSORT, smem, xin, Bpre, feat_all, el_all, er_all);
        return;
    }
    if (b < NBB) scanB1_body(b, smem, histT, bsum);
    gbar(&sortcnt[0], NSORT);
    if (b == 0) scanB2_body(smem, bsum, boff, histT, bstart);
    gbar(&sortcnt[1], NSORT);
    binC_body(b, smem, srci, dsti, reli, histT, boff, key_b);
    gbar(&sortcnt[2], NSORT);
    if (b < NBUCK) binD_body(b, smem, bstart, key_b, key_s, off);
}

// --------------------------------------------------------------------------
// K3 v6 (unchanged, verified): block = 32 dsts, wave = 8 dsts, 8 concurrent
// dsts x 8 feature-lanes, no cross-lane reduce.
// --------------------------------------------------------------------------
__global__ __launch_bounds__(256) void k3_node(
    const int* __restrict__ off, const int* __restrict__ key_s,
    const float* __restrict__ el_all, const float* __restrict__ er_all,
    const u16* __restrict__ feat_all, const void* __restrict__ bias,
    const int* __restrict__ flag, void* __restrict__ out)
{
    __shared__ int   ldsOffs[K3DPB + 1];
    __shared__ int   ldsKey[4][K3CAP];      // 2.5KB
    __shared__ float ldsEE[4][K3CAP][4];    // 10KB
    int t = threadIdx.x;
    int wave = t >> 6, lane = t & 63;
    int dg = lane >> 3;
    int fl = lane & 7;
    int h  = fl >> 1;
    int d0 = blockIdx.x * K3DPB;
    int isf32 = *flag;

    if (t < K3DPB + 1) ldsOffs[t] = off[min(d0 + t, NN)];
    __syncthreads();

    int dlo = wave * 8;
    int estart = ldsOffs[dlo], eend = ldsOffs[dlo + 8];
    int scount = min(eend - estart, K3CAP);

    int dbase = d0 & ~511;
    for (int j = lane; j < scount; j += 64) {
        int key = key_s[estart + j];
        int rel = (key >> 17) & 7, src = key & 131071;
        int d = dbase | ((key >> 20) & 511);
        int kk = rel * NN + src;
        f32x4 el = *(const f32x4*)&el_all[kk * 4];
        f32x4 er = *(const f32x4*)&er_all[(rel * NN + d) * 4];
        f32x4 ee;
#pragma unroll
        for (int q = 0; q < 4; ++q) {
            float v = el[q] + er[q];
            v = v > 0.f ? v : 0.2f * v;
            ee[q] = __expf(v);
        }
        ldsKey[wave][j] = kk;
        *(f32x4*)&ldsEE[wave][j][0] = ee;
    }

    float bv[8];
#pragma unroll
    for (int q = 0; q < 8; ++q) bv[q] = ldf(bias, fl * 8 + q, isf32);

    int nl = dlo + dg;
    int d = d0 + nl;
    int s  = ldsOffs[nl] - estart;
    int e1 = ldsOffs[nl + 1] - estart;
    float acc[8] = {0.f, 0.f, 0.f, 0.f, 0.f, 0.f, 0.f, 0.f};
    float accW = 0.f;

    int e1c = min(e1, K3CAP);
    for (int base = s; base < e1c; base += 4) {
        int kk[4]; float w[4];
#pragma unroll
        for (int q = 0; q < 4; ++q) {
            int idx = base + q;
            bool vld = idx < e1c;
            kk[q] = vld ? ldsKey[wave][idx] : ldsKey[wave][base];
            w[q]  = vld ? ldsEE[wave][idx][h] : 0.f;
        }
        uint4 u[4];
#pragma unroll
        for (int q = 0; q < 4; ++q)
            u[q] = *(const uint4*)&feat_all[kk[q] * 64 + fl * 8];
#pragma unroll
        for (int q = 0; q < 4; ++q) {
            acc[0] += bflo(u[q].x) * w[q];
            acc[1] += bfhi(u[q].x) * w[q];
            acc[2] += bflo(u[q].y) * w[q];
            acc[3] += bfhi(u[q].y) * w[q];
            acc[4] += bflo(u[q].z) * w[q];
            acc[5] += bfhi(u[q].z) * w[q];
            acc[6] += bflo(u[q].w) * w[q];
            acc[7] += bfhi(u[q].w) * w[q];
            accW += w[q];
        }
    }
    for (int j = max(s, K3CAP); j < e1; ++j) {
        int key = key_s[estart + j];
        int rel = (key >> 17) & 7, src = key & 131071;
        int kk0 = rel * NN + src;
        float v = el_all[kk0 * 4 + h] + er_all[(rel * NN + d) * 4 + h];
        v = v > 0.f ? v : 0.2f * v;
        float w0 = __expf(v);
        uint4 u = *(const uint4*)&feat_all[kk0 * 64 + fl * 8];
        acc[0] += bflo(u.x) * w0;
        acc[1] += bfhi(u.x) * w0;
        acc[2] += bflo(u.y) * w0;
        acc[3] += bfhi(u.y) * w0;
        acc[4] += bflo(u.z) * w0;
        acc[5] += bfhi(u.z) * w0;
        acc[6] += bflo(u.w) * w0;
        acc[7] += bfhi(u.w) * w0;
        accW += w0;
    }

    {
        float invh = 1.f / fmaxf(accW, 1e-16f);
        float o[8];
#pragma unroll
        for (int q = 0; q < 8; ++q) o[q] = acc[q] * invh + bv[q];
        if (isf32) {
            ((f32x4*)out)[d * 16 + fl * 2]     = f32x4{o[0], o[1], o[2], o[3]};
            ((f32x4*)out)[d * 16 + fl * 2 + 1] = f32x4{o[4], o[5], o[6], o[7]};
        } else {
            uint4 st;
            st.x = (u32)f2bf(o[0]) | ((u32)f2bf(o[1]) << 16);
            st.y = (u32)f2bf(o[2]) | ((u32)f2bf(o[3]) << 16);
            st.z = (u32)f2bf(o[4]) | ((u32)f2bf(o[5]) << 16);
            st.w = (u32)f2bf(o[6]) | ((u32)f2bf(o[7]) << 16);
            *(uint4*)&((u16*)out)[d * 64 + fl * 8] = st;
        }
    }
}

extern "C" void kernel_launch(void* const* d_in, const int* in_sizes, int n_in,
                              void* d_out, int out_size, void* d_ws, size_t ws_size,
                              hipStream_t stream)
{
    const void* x   = d_in[0];
    const int* srci = (const int*)d_in[1];
    const int* dsti = (const int*)d_in[2];
    const int* reli = (const int*)d_in[3];
    const void* cw  = d_in[4];
    const void* al  = d_in[5];
    const void* ar  = d_in[6];
    const void* hb  = d_in[7];

    // workspace layout (bytes, 16B-aligned), ~137.3 MB used
    char* ws = (char*)d_ws;
    u16*   feat_all = (u16*)  (ws + 0);            // 102,400,000
    float* el_all   = (float*)(ws + 102400000);    //  12,800,000
    float* er_all   = (float*)(ws + 115200000);    //  12,800,000
    int*   key_s    = (int*)  (ws + 128000000);    //   4,000,000
    int*   key_b    = (int*)  (ws + 132000000);    //   4,000,000
    int*   off      = (int*)  (ws + 136000000);    //     400,064
    int*   histT    = (int*)  (ws + 136400064);    //     765,968
    int*   bsum     = (int*)  (ws + 137166032);    //       3,008
    int*   boff     = (int*)  (ws + 137169040);    //       3,008
    int*   bstart   = (int*)  (ws + 137172048);    //         832
    u16*   Bpre     = (u16*)  (ws + 137172880);    //      81,920
    int*   flag     = (int*)  (ws + 137254800);    //           4
    int*   sortcnt  = (int*)  (ws + 137254816);    //          16

    k_pre<<<PRE_BLKS, 256, 0, stream>>>(x, flag, cw, al, ar, Bpre, dsti, histT,
                                        sortcnt);
    k_mid<<<NSORT + K1CH, 256, 0, stream>>>(x, Bpre, feat_all, el_all, er_all,
                                            srci, dsti, reli, histT, bsum, boff,
                                            bstart, key_b, key_s, off, sortcnt);
    k3_node<<<(NN + 31) / 32, 256, 0, stream>>>(off, key_s, el_all, er_all, feat_all,
                                                hb, flag, d_out);
}

// Round 10
// 202.863 us; speedup vs baseline: 2.4398x; 2.4398x over previous
//
#include <hip/hip_runtime.h>
#include <hip/hip_bf16.h>

#define NN 100000
#define NE 1000000
#define NR 8

// binned counting sort params
#define EB 1024
#define NBLK 977          // ceil(NE/EB)
#define NBUCK 196         // dst>>9 buckets
#define NT (NBUCK*NBLK)   // 191492 histogram cells
#define NBB 749           // ceil(NT/256)

#define K3DPB 32          // dsts per block in k3
#define K3CAP 160         // staged edges per wave (8 dsts, mean 80, sd ~9)

// fused pre-kernel block ranges
#define K0_BLKS  160      // NR*5120/256
#define PRE_BLKS (K0_BLKS + NBLK)

typedef unsigned short u16;
typedef unsigned int u32;
typedef __attribute__((ext_vector_type(8))) short bf16x8;
typedef __attribute__((ext_vector_type(4))) float f32x4;

static __device__ __forceinline__ float bf2f(u16 u) {
    union { u32 i; float f; } v; v.i = ((u32)u) << 16; return v.f;
}
static __device__ __forceinline__ float bflo(u32 u) {
    union { u32 i; float f; } v; v.i = u << 16; return v.f;
}
static __device__ __forceinline__ float bfhi(u32 u) {
    union { u32 i; float f; } v; v.i = u & 0xffff0000u; return v.f;
}
static __device__ __forceinline__ u16 f2bf(float f) {
    __hip_bfloat16 h = __float2bfloat16(f);
    return *reinterpret_cast<u16*>(&h);
}
static __device__ __forceinline__ float ldf(const void* p, int idx, int isf32) {
    return isf32 ? ((const float*)p)[idx] : bf2f(((const u16*)p)[idx]);
}

// detect helper: one wave scans first 512 u16 words of x; >50 insane => fp32
static __device__ __forceinline__ int detect_wave(const u16* xw, int lane)
{
    int insane = 0;
    for (int k = lane; k < 512; k += 64) {
        u16 w = xw[k];
        int ex = (w >> 7) & 0xFF;
        bool sane = ((w & 0x7FFF) == 0) || (ex >= 96 && ex <= 159);
        insane += sane ? 0 : 1;
    }
    for (int off = 32; off; off >>= 1) insane += __shfl_down(insane, off);
    return insane;   // valid in lane 0
}

// --------------------------------------------------------------------------
// k_pre: fused {k0_prep | binA} — independent work, one launch.
// --------------------------------------------------------------------------
__global__ __launch_bounds__(256) void k_pre(
    const void* __restrict__ xin, int* __restrict__ flag,
    const void* __restrict__ cw, const void* __restrict__ al,
    const void* __restrict__ ar, u16* __restrict__ Bpre,
    const int* __restrict__ dsti, int* __restrict__ histT)
{
    __shared__ int sflag;
    __shared__ int hist[NBUCK];
    int t = threadIdx.x;
    int b = blockIdx.x;

    if (b < K0_BLKS) {
        if (t < 64) {
            int insane = detect_wave((const u16*)xin, t);
            if (t == 0) {
                sflag = (insane > 50) ? 1 : 0;
                if (b == 0) *flag = sflag;
            }
        }
        __syncthreads();
        int isf32 = sflag;
        int tid = b * 256 + t;
        if (tid >= NR * 5120) return;
        int r = tid / 5120, rem = tid % 5120;
        int c = rem >> 3, j = rem & 7;
        int nt = c >> 7, kk = (c >> 6) & 1, lc = c & 63;
        int i = kk * 32 + ((lc >> 4) << 3) + j;
        int d = lc & 15;
        u16 val;
        if (nt < 4) {
            val = f2bf(ldf(cw, ((r * 4 + nt) * 64 + i) * 16 + d, isf32));
        } else if (d < 8) {
            int h = d >> 1;
            const void* attn = (d & 1) ? ar : al;
            float s = 0.f;
            for (int dd = 0; dd < 16; ++dd)
                s += ldf(cw, ((r * 4 + h) * 64 + i) * 16 + dd, isf32)
                   * ldf(attn, (r * 4 + h) * 16 + dd, isf32);
            val = f2bf(s);
        } else {
            val = 0;
        }
        Bpre[tid] = val;
    } else {
        int blk = b - K0_BLKS;
        if (t < NBUCK) hist[t] = 0;
        __syncthreads();
        int base = blk * EB;
        for (int j = 0; j < EB; j += 256) {
            int e = base + j + t;
            if (e < NE) atomicAdd(&hist[dsti[e] >> 9], 1);
        }
        __syncthreads();
        if (t < NBUCK) histT[t * NBLK + blk] = hist[t];
    }
}

// --------------------------------------------------------------------------
// K1 v8 (verified round 7: 47us, 0 conflicts, FETCH 13MB, WRITE 125MB):
// all 8 rels per 64-node chunk, transposed MFMA, packed swizzled LDS,
// coalesced copy-out, 8 barriers/block.
// --------------------------------------------------------------------------
__global__ __launch_bounds__(256) void k1_feat(
    const void* __restrict__ xin, const u16* __restrict__ Bpre,
    u16* __restrict__ feat_all, float* __restrict__ el_all, float* __restrict__ er_all)
{
    __shared__ u32 ldsT[2][64][32];        // 16 KB
    int n0 = blockIdx.x * 64;
    int tid = threadIdx.x;
    int wave = tid >> 6, lane = tid & 63;
    int col = lane & 15, quad = lane >> 4;

    // per-wave detect, no barrier (1KB, cache-hot)
    int insane = detect_wave((const u16*)xin, lane);
    insane = __shfl(insane, 0);
    int isf32 = (insane > 50) ? 1 : 0;

    int node = n0 + wave * 16 + col;       // transposed: col indexes the node
    int nclamp = node < NN ? node : NN - 1;
    bool nvalid = node < NN;

    // A-fragments (MFMA B-operand): lane reads 8 contiguous bf16 -> 16B load
    bf16x8 afrag0, afrag1;
    if (!isf32) {
        const u16* xb = (const u16*)xin + nclamp * 64 + quad * 8;
        afrag0 = *(const bf16x8*)&xb[0];
        afrag1 = *(const bf16x8*)&xb[32];
    } else {
        const float* xf = (const float*)xin + nclamp * 64 + quad * 8;
#pragma unroll
        for (int j = 0; j < 8; ++j) {
            afrag0[j] = (short)f2bf(xf[j]);
            afrag1[j] = (short)f2bf(xf[32 + j]);
        }
    }

#pragma unroll 1
    for (int ch = 0; ch < 4; ++ch) {
#pragma unroll
        for (int rr = 0; rr < 2; ++rr) {
            int r = ch * 2 + rr;
            f32x4 acc[5];
#pragma unroll
            for (int nt = 0; nt < 5; ++nt) acc[nt] = f32x4{0.f, 0.f, 0.f, 0.f};
#pragma unroll
            for (int nt = 0; nt < 5; ++nt) {
                bf16x8 b0 = *(const bf16x8*)&Bpre[r * 5120 + ((nt * 2 + 0) * 64 + lane) * 8];
                bf16x8 b1 = *(const bf16x8*)&Bpre[r * 5120 + ((nt * 2 + 1) * 64 + lane) * 8];
                // W-frag as A-operand, X-frag as B-operand  =>  D = (X·W)^T
                acc[nt] = __builtin_amdgcn_mfma_f32_16x16x32_bf16(b0, afrag0, acc[nt], 0, 0, 0);
                acc[nt] = __builtin_amdgcn_mfma_f32_16x16x32_bf16(b1, afrag1, acc[nt], 0, 0, 0);
            }

            // pack 4 consecutive features -> one 8B LDS write per tile (swizzled)
#pragma unroll
            for (int nt = 0; nt < 4; ++nt) {
                u32 lo = (u32)f2bf(acc[nt][0]) | ((u32)f2bf(acc[nt][1]) << 16);
                u32 hi = (u32)f2bf(acc[nt][2]) | ((u32)f2bf(acc[nt][3]) << 16);
                int w = (nt * 8 + quad * 2) ^ (col * 2);
                *(uint2*)&ldsT[rr][wave * 16 + col][w] = uint2{lo, hi};
            }
            if (nvalid && quad < 2) {
                // tile4 rows: quad0 -> {el_h0, er_h0, el_h1, er_h1},
                //             quad1 -> {el_h2, er_h2, el_h3, er_h3}
                int eb = (r * NN + node) * 4 + quad * 2;
                *(float2*)&el_all[eb] = float2{acc[4][0], acc[4][2]};
                *(float2*)&er_all[eb] = float2{acc[4][1], acc[4][3]};
            }
        }
        __syncthreads();   // both rel tiles of this chunk staged

        // coalesced copy-out: 2048 uint2 over 256 threads
#pragma unroll
        for (int it = 0; it < 8; ++it) {
            int u = it * 256 + tid;
            int rr = u >> 10;
            int v = u & 1023;
            int nl = v >> 4;              // node within chunk
            int p  = v & 15;              // uint2 within node row
            int w  = (p * 2) ^ ((nl & 15) * 2);
            uint2 val = *(const uint2*)&ldsT[rr][nl][w];
            int nd = n0 + nl;
            if (nd < NN)
                *(uint2*)&feat_all[((ch * 2 + rr) * NN + nd) * 64 + p * 4] = val;
        }
        __syncthreads();   // ldsT fully drained before next chunk overwrites
    }
}

// --------------------------------------------------------------------------
// Counting-sort scans.
// --------------------------------------------------------------------------
__global__ __launch_bounds__(256) void k_scanB1(int* __restrict__ histT,
                                                int* __restrict__ bsum)
{
    __shared__ int wtot[4];
    int t = threadIdx.x;
    int gi = blockIdx.x * 256 + t;
    int v = (gi < NT) ? histT[gi] : 0;
    int lane = t & 63, w = t >> 6;
    int s = v;
#pragma unroll
    for (int m = 1; m < 64; m <<= 1) {
        int u = __shfl_up(s, m);
        if (lane >= m) s += u;
    }
    if (lane == 63) wtot[w] = s;
    __syncthreads();
    int wb = 0;
    for (int i = 0; i < w; ++i) wb += wtot[i];
    if (gi < NT) histT[gi] = wb + s - v;
    if (t == 255) bsum[blockIdx.x] = wb + s;
}

// scanB2 + bstart emission
__global__ __launch_bounds__(1024) void k_scanB2(const int* __restrict__ bsum,
                                                 int* __restrict__ boff,
                                                 const int* __restrict__ histT,
                                                 int* __restrict__ bstart)
{
    __shared__ int wtot[16];
    __shared__ int sboff[NBB];
    int t = threadIdx.x;
    int v = (t < NBB) ? bsum[t] : 0;
    int lane = t & 63, w = t >> 6;
    int s = v;
#pragma unroll
    for (int m = 1; m < 64; m <<= 1) {
        int u = __shfl_up(s, m);
        if (lane >= m) s += u;
    }
    if (lane == 63) wtot[w] = s;
    __syncthreads();
    int wb = 0;
    for (int i = 0; i < w; ++i) wb += wtot[i];
    if (t < NBB) {
        int val = wb + s - v;
        boff[t] = val;
        sboff[t] = val;
    }
    __syncthreads();
    if (t < NBUCK) {
        int gi = t * NBLK;
        bstart[t] = histT[gi] + sboff[gi >> 8];
    }
    if (t == 0) bstart[NBUCK] = NE;
}

// key = (dst&511)<<20 | rel<<17 | src   (29 bits)
__global__ __launch_bounds__(256) void k_binC(
    const int* __restrict__ srci, const int* __restrict__ dsti,
    const int* __restrict__ reli, const int* __restrict__ histT,
    const int* __restrict__ boff, int* __restrict__ key_b)
{
    __shared__ int cur[NBUCK];
    int t = threadIdx.x, blk = blockIdx.x;
    if (t < NBUCK) {
        int gi = t * NBLK + blk;
        cur[t] = histT[gi] + boff[gi >> 8];
    }
    __syncthreads();
    int base = blk * EB;
    for (int j = 0; j < EB; j += 256) {
        int e = base + j + t;
        if (e < NE) {
            int d = dsti[e];
            int key = ((d & 511) << 20) | (reli[e] << 17) | srci[e];
            int pos = atomicAdd(&cur[d >> 9], 1);
            key_b[pos] = key;
        }
    }
}

__global__ __launch_bounds__(1024) void k_binD(
    const int* __restrict__ bstart, const int* __restrict__ key_b,
    int* __restrict__ key_s, int* __restrict__ off)
{
    __shared__ int cnt[512];
    __shared__ int wtot[8];
    int t = threadIdx.x, b = blockIdx.x;
    int s0 = bstart[b], s1 = bstart[b + 1];
    if (t < 512) cnt[t] = 0;
    __syncthreads();
    for (int j = s0 + t; j < s1; j += 1024)
        atomicAdd(&cnt[(key_b[j] >> 20) & 511], 1);
    __syncthreads();
    int excl = 0;
    if (t < 512) {
        int v = cnt[t];
        int lane = t & 63, w = t >> 6;
        int s = v;
#pragma unroll
        for (int m = 1; m < 64; m <<= 1) {
            int u = __shfl_up(s, m);
            if (lane >= m) s += u;
        }
        if (lane == 63) wtot[w] = s;
        __syncthreads();
        int wb = 0;
        for (int i = 0; i < w; ++i) wb += wtot[i];
        excl = s0 + wb + s - v;
        int d = (b << 9) + t;
        if (d < NN) off[d] = excl;
    } else {
        __syncthreads();
    }
    __syncthreads();
    if (t < 512) cnt[t] = excl;
    if (b == 0 && t == 0) off[NN] = NE;
    __syncthreads();
    for (int j = s0 + t; j < s1; j += 1024) {
        int key = key_b[j];
        int pos = atomicAdd(&cnt[(key >> 20) & 511], 1);
        key_s[pos] = key;
    }
}

// --------------------------------------------------------------------------
// K3 v6 (verified): block = 32 dsts, wave = 8 dsts, 8 concurrent dsts x
// 8 feature-lanes, no cross-lane reduce.
// --------------------------------------------------------------------------
__global__ __launch_bounds__(256) void k3_node(
    const int* __restrict__ off, const int* __restrict__ key_s,
    const float* __restrict__ el_all, const float* __restrict__ er_all,
    const u16* __restrict__ feat_all, const void* __restrict__ bias,
    const int* __restrict__ flag, void* __restrict__ out)
{
    __shared__ int   ldsOffs[K3DPB + 1];
    __shared__ int   ldsKey[4][K3CAP];      // 2.5KB
    __shared__ float ldsEE[4][K3CAP][4];    // 10KB
    int t = threadIdx.x;
    int wave = t >> 6, lane = t & 63;
    int dg = lane >> 3;
    int fl = lane & 7;
    int h  = fl >> 1;
    int d0 = blockIdx.x * K3DPB;
    int isf32 = *flag;

    if (t < K3DPB + 1) ldsOffs[t] = off[min(d0 + t, NN)];
    __syncthreads();

    int dlo = wave * 8;
    int estart = ldsOffs[dlo], eend = ldsOffs[dlo + 8];
    int scount = min(eend - estart, K3CAP);

    int dbase = d0 & ~511;
    for (int j = lane; j < scount; j += 64) {
        int key = key_s[estart + j];
        int rel = (key >> 17) & 7, src = key & 131071;
        int d = dbase | ((key >> 20) & 511);
        int kk = rel * NN + src;
        f32x4 el = *(const f32x4*)&el_all[kk * 4];
        f32x4 er = *(const f32x4*)&er_all[(rel * NN + d) * 4];
        f32x4 ee;
#pragma unroll
        for (int q = 0; q < 4; ++q) {
            float v = el[q] + er[q];
            v = v > 0.f ? v : 0.2f * v;
            ee[q] = __expf(v);
        }
        ldsKey[wave][j] = kk;
        *(f32x4*)&ldsEE[wave][j][0] = ee;
    }
    // same-wave LDS write->read ordered via lgkmcnt

    float bv[8];
#pragma unroll
    for (int q = 0; q < 8; ++q) bv[q] = ldf(bias, fl * 8 + q, isf32);

    int nl = dlo + dg;
    int d = d0 + nl;
    int s  = ldsOffs[nl] - estart;
    int e1 = ldsOffs[nl + 1] - estart;
    float acc[8] = {0.f, 0.f, 0.f, 0.f, 0.f, 0.f, 0.f, 0.f};
    float accW = 0.f;

    int e1c = min(e1, K3CAP);
    for (int base = s; base < e1c; base += 4) {
        int kk[4]; float w[4];
#pragma unroll
        for (int q = 0; q < 4; ++q) {
            int idx = base + q;
            bool vld = idx < e1c;
            kk[q] = vld ? ldsKey[wave][idx] : ldsKey[wave][base];
            w[q]  = vld ? ldsEE[wave][idx][h] : 0.f;
        }
        uint4 u[4];
#pragma unroll
        for (int q = 0; q < 4; ++q)
            u[q] = *(const uint4*)&feat_all[kk[q] * 64 + fl * 8];
#pragma unroll
        for (int q = 0; q < 4; ++q) {
            acc[0] += bflo(u[q].x) * w[q];
            acc[1] += bfhi(u[q].x) * w[q];
            acc[2] += bflo(u[q].y) * w[q];
            acc[3] += bfhi(u[q].y) * w[q];
            acc[4] += bflo(u[q].z) * w[q];
            acc[5] += bfhi(u[q].z) * w[q];
            acc[6] += bflo(u[q].w) * w[q];
            acc[7] += bfhi(u[q].w) * w[q];
            accW += w[q];
        }
    }
    // overflow path (statistically never; correctness fallback)
    for (int j = max(s, K3CAP); j < e1; ++j) {
        int key = key_s[estart + j];
        int rel = (key >> 17) & 7, src = key & 131071;
        int kk0 = rel * NN + src;
        float v = el_all[kk0 * 4 + h] + er_all[(rel * NN + d) * 4 + h];
        v = v > 0.f ? v : 0.2f * v;
        float w0 = __expf(v);
        uint4 u = *(const uint4*)&feat_all[kk0 * 64 + fl * 8];
        acc[0] += bflo(u.x) * w0;
        acc[1] += bfhi(u.x) * w0;
        acc[2] += bflo(u.y) * w0;
        acc[3] += bfhi(u.y) * w0;
        acc[4] += bflo(u.z) * w0;
        acc[5] += bfhi(u.z) * w0;
        acc[6] += bflo(u.w) * w0;
        acc[7] += bfhi(u.w) * w0;
        accW += w0;
    }

    {
        float invh = 1.f / fmaxf(accW, 1e-16f);
        float o[8];
#pragma unroll
        for (int q = 0; q < 8; ++q) o[q] = acc[q] * invh + bv[q];
        if (isf32) {
            ((f32x4*)out)[d * 16 + fl * 2]     = f32x4{o[0], o[1], o[2], o[3]};
            ((f32x4*)out)[d * 16 + fl * 2 + 1] = f32x4{o[4], o[5], o[6], o[7]};
        } else {
            uint4 st;
            st.x = (u32)f2bf(o[0]) | ((u32)f2bf(o[1]) << 16);
            st.y = (u32)f2bf(o[2]) | ((u32)f2bf(o[3]) << 16);
            st.z = (u32)f2bf(o[4]) | ((u32)f2bf(o[5]) << 16);
            st.w = (u32)f2bf(o[6]) | ((u32)f2bf(o[7]) << 16);
            *(uint4*)&((u16*)out)[d * 64 + fl * 8] = st;
        }
    }
}

extern "C" void kernel_launch(void* const* d_in, const int* in_sizes, int n_in,
                              void* d_out, int out_size, void* d_ws, size_t ws_size,
                              hipStream_t stream)
{
    const void* x   = d_in[0];
    const int* srci = (const int*)d_in[1];
    const int* dsti = (const int*)d_in[2];
    const int* reli = (const int*)d_in[3];
    const void* cw  = d_in[4];
    const void* al  = d_in[5];
    const void* ar  = d_in[6];
    const void* hb  = d_in[7];

    // workspace layout (bytes, 16B-aligned), ~137.3 MB used
    char* ws = (char*)d_ws;
    u16*   feat_all = (u16*)  (ws + 0);            // 102,400,000
    float* el_all   = (float*)(ws + 102400000);    //  12,800,000
    float* er_all   = (float*)(ws + 115200000);    //  12,800,000
    int*   key_s    = (int*)  (ws + 128000000);    //   4,000,000
    int*   key_b    = (int*)  (ws + 132000000);    //   4,000,000
    int*   off      = (int*)  (ws + 136000000);    //     400,064
    int*   histT    = (int*)  (ws + 136400064);    //     765,968
    int*   bsum     = (int*)  (ws + 137166032);    //       3,008
    int*   boff     = (int*)  (ws + 137169040);    //       3,008
    int*   bstart   = (int*)  (ws + 137172048);    //         832
    u16*   Bpre     = (u16*)  (ws + 137172880);    //      81,920
    int*   flag     = (int*)  (ws + 137254800);    //           4

    k_pre<<<PRE_BLKS, 256, 0, stream>>>(x, flag, cw, al, ar, Bpre, dsti, histT);
    k1_feat<<<(NN + 63) / 64, 256, 0, stream>>>(x, Bpre, feat_all, el_all, er_all);
    k_scanB1<<<NBB, 256, 0, stream>>>(histT, bsum);
    k_scanB2<<<1, 1024, 0, stream>>>(bsum, boff, histT, bstart);
    k_binC<<<NBLK, 256, 0, stream>>>(srci, dsti, reli, histT, boff, key_b);
    k_binD<<<NBUCK, 1024, 0, stream>>>(bstart, key_b, key_s, off);
    k3_node<<<(NN + 31) / 32, 256, 0, stream>>>(off, key_s, el_all, er_all, feat_all,
                                                hb, flag, d_out);
}

// Round 11
// 198.702 us; speedup vs baseline: 2.4909x; 1.0209x over previous
//
#include <hip/hip_runtime.h>
#include <hip/hip_bf16.h>

#define NN 100000
#define NE 1000000
#define NR 8

// binned counting sort params
#define EB 1024
#define NBLK 977          // ceil(NE/EB)
#define NBUCK 196         // dst>>9 buckets
#define NT (NBUCK*NBLK)   // 191492 histogram cells
#define NBB 749           // ceil(NT/256)

#define K3DPB 32          // dsts per block in k3
#define K3CAP 160         // staged edges per wave (8 dsts, mean 80, sd ~9)

// fused pre-kernel block ranges
#define K0_BLKS  160      // NR*5120/256
#define PRE_BLKS (K0_BLKS + NBLK)

// k1 launch: full unsliced k1 (blockIdx 0..K1B-1) + scanB1 riders
// (blockIdx K1B..K1B+NBB-1). scanB1 depends only on k_pre, and the two
// groups never wait on each other -> safe for any dispatch order.
#define K1B 1563

typedef unsigned short u16;
typedef unsigned int u32;
typedef __attribute__((ext_vector_type(8))) short bf16x8;
typedef __attribute__((ext_vector_type(4))) float f32x4;

static __device__ __forceinline__ float bf2f(u16 u) {
    union { u32 i; float f; } v; v.i = ((u32)u) << 16; return v.f;
}
static __device__ __forceinline__ float bflo(u32 u) {
    union { u32 i; float f; } v; v.i = u << 16; return v.f;
}
static __device__ __forceinline__ float bfhi(u32 u) {
    union { u32 i; float f; } v; v.i = u & 0xffff0000u; return v.f;
}
static __device__ __forceinline__ u16 f2bf(float f) {
    __hip_bfloat16 h = __float2bfloat16(f);
    return *reinterpret_cast<u16*>(&h);
}
static __device__ __forceinline__ float ldf(const void* p, int idx, int isf32) {
    return isf32 ? ((const float*)p)[idx] : bf2f(((const u16*)p)[idx]);
}

// detect helper: one wave scans first 512 u16 words of x; >50 insane => fp32
static __device__ __forceinline__ int detect_wave(const u16* xw, int lane)
{
    int insane = 0;
    for (int k = lane; k < 512; k += 64) {
        u16 w = xw[k];
        int ex = (w >> 7) & 0xFF;
        bool sane = ((w & 0x7FFF) == 0) || (ex >= 96 && ex <= 159);
        insane += sane ? 0 : 1;
    }
    for (int off = 32; off; off >>= 1) insane += __shfl_down(insane, off);
    return insane;   // valid in lane 0
}

// --------------------------------------------------------------------------
// k_pre: fused {k0_prep | binA} — independent work, one launch. (unchanged)
// --------------------------------------------------------------------------
__global__ __launch_bounds__(256) void k_pre(
    const void* __restrict__ xin, int* __restrict__ flag,
    const void* __restrict__ cw, const void* __restrict__ al,
    const void* __restrict__ ar, u16* __restrict__ Bpre,
    const int* __restrict__ dsti, int* __restrict__ histT)
{
    __shared__ int sflag;
    __shared__ int hist[NBUCK];
    int t = threadIdx.x;
    int b = blockIdx.x;

    if (b < K0_BLKS) {
        if (t < 64) {
            int insane = detect_wave((const u16*)xin, t);
            if (t == 0) {
                sflag = (insane > 50) ? 1 : 0;
                if (b == 0) *flag = sflag;
            }
        }
        __syncthreads();
        int isf32 = sflag;
        int tid = b * 256 + t;
        if (tid >= NR * 5120) return;
        int r = tid / 5120, rem = tid % 5120;
        int c = rem >> 3, j = rem & 7;
        int nt = c >> 7, kk = (c >> 6) & 1, lc = c & 63;
        int i = kk * 32 + ((lc >> 4) << 3) + j;
        int d = lc & 15;
        u16 val;
        if (nt < 4) {
            val = f2bf(ldf(cw, ((r * 4 + nt) * 64 + i) * 16 + d, isf32));
        } else if (d < 8) {
            int h = d >> 1;
            const void* attn = (d & 1) ? ar : al;
            float s = 0.f;
            for (int dd = 0; dd < 16; ++dd)
                s += ldf(cw, ((r * 4 + h) * 64 + i) * 16 + dd, isf32)
                   * ldf(attn, (r * 4 + h) * 16 + dd, isf32);
            val = f2bf(s);
        } else {
            val = 0;
        }
        Bpre[tid] = val;
    } else {
        int blk = b - K0_BLKS;
        if (t < NBUCK) hist[t] = 0;
        __syncthreads();
        int base = blk * EB;
        for (int j = 0; j < EB; j += 256) {
            int e = base + j + t;
            if (e < NE) atomicAdd(&hist[dsti[e] >> 9], 1);
        }
        __syncthreads();
        if (t < NBUCK) histT[t * NBLK + blk] = hist[t];
    }
}

// --------------------------------------------------------------------------
// K1 v9 = verified v8 body (45us, 0 conflicts, FETCH 13MB, WRITE 125MB)
// + scanB1 rider blocks in the SAME launch. scanB1 depends only on k_pre;
// k1 and scanB1 blocks never interact (block-granular branch, no barriers,
// no slicing) -> round-8/9 failure modes structurally excluded. Saves one
// launch gap and hides scanB1 under k1.
// --------------------------------------------------------------------------
__global__ __launch_bounds__(256) void k1_feat(
    const void* __restrict__ xin, const u16* __restrict__ Bpre,
    u16* __restrict__ feat_all, float* __restrict__ el_all, float* __restrict__ er_all,
    int* __restrict__ histT, int* __restrict__ bsum)
{
    __shared__ u32 ldsT[2][64][32];        // 16 KB (scanB1 path reuses 16B)
    int bid = blockIdx.x;
    int tid = threadIdx.x;

    if (bid >= K1B) {
        // ---- scanB1 rider: 256-wide exclusive scan of one histT chunk ----
        int b = bid - K1B;
        int* wtot = (int*)&ldsT[0][0][0];
        int t = tid;
        int gi = b * 256 + t;
        int v = (gi < NT) ? histT[gi] : 0;
        int lane = t & 63, w = t >> 6;
        int s = v;
#pragma unroll
        for (int m = 1; m < 64; m <<= 1) {
            int u = __shfl_up(s, m);
            if (lane >= m) s += u;
        }
        if (lane == 63) wtot[w] = s;
        __syncthreads();
        int wb = 0;
        for (int i = 0; i < w; ++i) wb += wtot[i];
        if (gi < NT) histT[gi] = wb + s - v;
        if (t == 255) bsum[b] = wb + s;
        return;
    }

    // ---- k1 path (verified v8 body, unchanged) ----
    int n0 = bid * 64;
    int wave = tid >> 6, lane = tid & 63;
    int col = lane & 15, quad = lane >> 4;

    // per-wave detect, no barrier (1KB, cache-hot)
    int insane = detect_wave((const u16*)xin, lane);
    insane = __shfl(insane, 0);
    int isf32 = (insane > 50) ? 1 : 0;

    int node = n0 + wave * 16 + col;       // transposed: col indexes the node
    int nclamp = node < NN ? node : NN - 1;
    bool nvalid = node < NN;

    // A-fragments (MFMA B-operand): lane reads 8 contiguous bf16 -> 16B load
    bf16x8 afrag0, afrag1;
    if (!isf32) {
        const u16* xb = (const u16*)xin + nclamp * 64 + quad * 8;
        afrag0 = *(const bf16x8*)&xb[0];
        afrag1 = *(const bf16x8*)&xb[32];
    } else {
        const float* xf = (const float*)xin + nclamp * 64 + quad * 8;
#pragma unroll
        for (int j = 0; j < 8; ++j) {
            afrag0[j] = (short)f2bf(xf[j]);
            afrag1[j] = (short)f2bf(xf[32 + j]);
        }
    }

#pragma unroll 1
    for (int ch = 0; ch < 4; ++ch) {
#pragma unroll
        for (int rr = 0; rr < 2; ++rr) {
            int r = ch * 2 + rr;
            f32x4 acc[5];
#pragma unroll
            for (int nt = 0; nt < 5; ++nt) acc[nt] = f32x4{0.f, 0.f, 0.f, 0.f};
#pragma unroll
            for (int nt = 0; nt < 5; ++nt) {
                bf16x8 b0 = *(const bf16x8*)&Bpre[r * 5120 + ((nt * 2 + 0) * 64 + lane) * 8];
                bf16x8 b1 = *(const bf16x8*)&Bpre[r * 5120 + ((nt * 2 + 1) * 64 + lane) * 8];
                // W-frag as A-operand, X-frag as B-operand  =>  D = (X·W)^T
                acc[nt] = __builtin_amdgcn_mfma_f32_16x16x32_bf16(b0, afrag0, acc[nt], 0, 0, 0);
                acc[nt] = __builtin_amdgcn_mfma_f32_16x16x32_bf16(b1, afrag1, acc[nt], 0, 0, 0);
            }

            // pack 4 consecutive features -> one 8B LDS write per tile (swizzled)
#pragma unroll
            for (int nt = 0; nt < 4; ++nt) {
                u32 lo = (u32)f2bf(acc[nt][0]) | ((u32)f2bf(acc[nt][1]) << 16);
                u32 hi = (u32)f2bf(acc[nt][2]) | ((u32)f2bf(acc[nt][3]) << 16);
                int w = (nt * 8 + quad * 2) ^ (col * 2);
                *(uint2*)&ldsT[rr][wave * 16 + col][w] = uint2{lo, hi};
            }
            if (nvalid && quad < 2) {
                // tile4 rows: quad0 -> {el_h0, er_h0, el_h1, er_h1},
                //             quad1 -> {el_h2, er_h2, el_h3, er_h3}
                int eb = (r * NN + node) * 4 + quad * 2;
                *(float2*)&el_all[eb] = float2{acc[4][0], acc[4][2]};
                *(float2*)&er_all[eb] = float2{acc[4][1], acc[4][3]};
            }
        }
        __syncthreads();   // both rel tiles of this chunk staged

        // coalesced copy-out: 2048 uint2 over 256 threads
#pragma unroll
        for (int it = 0; it < 8; ++it) {
            int u = it * 256 + tid;
            int rr = u >> 10;
            int v = u & 1023;
            int nl = v >> 4;              // node within chunk
            int p  = v & 15;              // uint2 within node row
            int w  = (p * 2) ^ ((nl & 15) * 2);
            uint2 val = *(const uint2*)&ldsT[rr][nl][w];
            int nd = n0 + nl;
            if (nd < NN)
                *(uint2*)&feat_all[((ch * 2 + rr) * NN + nd) * 64 + p * 4] = val;
        }
        __syncthreads();   // ldsT fully drained before next chunk overwrites
    }
}

// --------------------------------------------------------------------------
// Counting-sort tail (scanB1 now rides in the k1 launch).
// --------------------------------------------------------------------------
// scanB2 + bstart emission
__global__ __launch_bounds__(1024) void k_scanB2(const int* __restrict__ bsum,
                                                 int* __restrict__ boff,
                                                 const int* __restrict__ histT,
                                                 int* __restrict__ bstart)
{
    __shared__ int wtot[16];
    __shared__ int sboff[NBB];
    int t = threadIdx.x;
    int v = (t < NBB) ? bsum[t] : 0;
    int lane = t & 63, w = t >> 6;
    int s = v;
#pragma unroll
    for (int m = 1; m < 64; m <<= 1) {
        int u = __shfl_up(s, m);
        if (lane >= m) s += u;
    }
    if (lane == 63) wtot[w] = s;
    __syncthreads();
    int wb = 0;
    for (int i = 0; i < w; ++i) wb += wtot[i];
    if (t < NBB) {
        int val = wb + s - v;
        boff[t] = val;
        sboff[t] = val;
    }
    __syncthreads();
    if (t < NBUCK) {
        int gi = t * NBLK;
        bstart[t] = histT[gi] + sboff[gi >> 8];
    }
    if (t == 0) bstart[NBUCK] = NE;
}

// key = (dst&511)<<20 | rel<<17 | src   (29 bits)
__global__ __launch_bounds__(256) void k_binC(
    const int* __restrict__ srci, const int* __restrict__ dsti,
    const int* __restrict__ reli, const int* __restrict__ histT,
    const int* __restrict__ boff, int* __restrict__ key_b)
{
    __shared__ int cur[NBUCK];
    int t = threadIdx.x, blk = blockIdx.x;
    if (t < NBUCK) {
        int gi = t * NBLK + blk;
        cur[t] = histT[gi] + boff[gi >> 8];
    }
    __syncthreads();
    int base = blk * EB;
    for (int j = 0; j < EB; j += 256) {
        int e = base + j + t;
        if (e < NE) {
            int d = dsti[e];
            int key = ((d & 511) << 20) | (reli[e] << 17) | srci[e];
            int pos = atomicAdd(&cur[d >> 9], 1);
            key_b[pos] = key;
        }
    }
}

__global__ __launch_bounds__(1024) void k_binD(
    const int* __restrict__ bstart, const int* __restrict__ key_b,
    int* __restrict__ key_s, int* __restrict__ off)
{
    __shared__ int cnt[512];
    __shared__ int wtot[8];
    int t = threadIdx.x, b = blockIdx.x;
    int s0 = bstart[b], s1 = bstart[b + 1];
    if (t < 512) cnt[t] = 0;
    __syncthreads();
    for (int j = s0 + t; j < s1; j += 1024)
        atomicAdd(&cnt[(key_b[j] >> 20) & 511], 1);
    __syncthreads();
    int excl = 0;
    if (t < 512) {
        int v = cnt[t];
        int lane = t & 63, w = t >> 6;
        int s = v;
#pragma unroll
        for (int m = 1; m < 64; m <<= 1) {
            int u = __shfl_up(s, m);
            if (lane >= m) s += u;
        }
        if (lane == 63) wtot[w] = s;
        __syncthreads();
        int wb = 0;
        for (int i = 0; i < w; ++i) wb += wtot[i];
        excl = s0 + wb + s - v;
        int d = (b << 9) + t;
        if (d < NN) off[d] = excl;
    } else {
        __syncthreads();
    }
    __syncthreads();
    if (t < 512) cnt[t] = excl;
    if (b == 0 && t == 0) off[NN] = NE;
    __syncthreads();
    for (int j = s0 + t; j < s1; j += 1024) {
        int key = key_b[j];
        int pos = atomicAdd(&cnt[(key >> 20) & 511], 1);
        key_s[pos] = key;
    }
}

// --------------------------------------------------------------------------
// K3 v6 (verified): block = 32 dsts, wave = 8 dsts, 8 concurrent dsts x
// 8 feature-lanes, no cross-lane reduce.
// --------------------------------------------------------------------------
__global__ __launch_bounds__(256) void k3_node(
    const int* __restrict__ off, const int* __restrict__ key_s,
    const float* __restrict__ el_all, const float* __restrict__ er_all,
    const u16* __restrict__ feat_all, const void* __restrict__ bias,
    const int* __restrict__ flag, void* __restrict__ out)
{
    __shared__ int   ldsOffs[K3DPB + 1];
    __shared__ int   ldsKey[4][K3CAP];      // 2.5KB
    __shared__ float ldsEE[4][K3CAP][4];    // 10KB
    int t = threadIdx.x;
    int wave = t >> 6, lane = t & 63;
    int dg = lane >> 3;
    int fl = lane & 7;
    int h  = fl >> 1;
    int d0 = blockIdx.x * K3DPB;
    int isf32 = *flag;

    if (t < K3DPB + 1) ldsOffs[t] = off[min(d0 + t, NN)];
    __syncthreads();

    int dlo = wave * 8;
    int estart = ldsOffs[dlo], eend = ldsOffs[dlo + 8];
    int scount = min(eend - estart, K3CAP);

    int dbase = d0 & ~511;
    for (int j = lane; j < scount; j += 64) {
        int key = key_s[estart + j];
        int rel = (key >> 17) & 7, src = key & 131071;
        int d = dbase | ((key >> 20) & 511);
        int kk = rel * NN + src;
        f32x4 el = *(const f32x4*)&el_all[kk * 4];
        f32x4 er = *(const f32x4*)&er_all[(rel * NN + d) * 4];
        f32x4 ee;
#pragma unroll
        for (int q = 0; q < 4; ++q) {
            float v = el[q] + er[q];
            v = v > 0.f ? v : 0.2f * v;
            ee[q] = __expf(v);
        }
        ldsKey[wave][j] = kk;
        *(f32x4*)&ldsEE[wave][j][0] = ee;
    }
    // same-wave LDS write->read ordered via lgkmcnt

    float bv[8];
#pragma unroll
    for (int q = 0; q < 8; ++q) bv[q] = ldf(bias, fl * 8 + q, isf32);

    int nl = dlo + dg;
    int d = d0 + nl;
    int s  = ldsOffs[nl] - estart;
    int e1 = ldsOffs[nl + 1] - estart;
    float acc[8] = {0.f, 0.f, 0.f, 0.f, 0.f, 0.f, 0.f, 0.f};
    float accW = 0.f;

    int e1c = min(e1, K3CAP);
    for (int base = s; base < e1c; base += 4) {
        int kk[4]; float w[4];
#pragma unroll
        for (int q = 0; q < 4; ++q) {
            int idx = base + q;
            bool vld = idx < e1c;
            kk[q] = vld ? ldsKey[wave][idx] : ldsKey[wave][base];
            w[q]  = vld ? ldsEE[wave][idx][h] : 0.f;
        }
        uint4 u[4];
#pragma unroll
        for (int q = 0; q < 4; ++q)
            u[q] = *(const uint4*)&feat_all[kk[q] * 64 + fl * 8];
#pragma unroll
        for (int q = 0; q < 4; ++q) {
            acc[0] += bflo(u[q].x) * w[q];
            acc[1] += bfhi(u[q].x) * w[q];
            acc[2] += bflo(u[q].y) * w[q];
            acc[3] += bfhi(u[q].y) * w[q];
            acc[4] += bflo(u[q].z) * w[q];
            acc[5] += bfhi(u[q].z) * w[q];
            acc[6] += bflo(u[q].w) * w[q];
            acc[7] += bfhi(u[q].w) * w[q];
            accW += w[q];
        }
    }
    // overflow path (statistically never; correctness fallback)
    for (int j = max(s, K3CAP); j < e1; ++j) {
        int key = key_s[estart + j];
        int rel = (key >> 17) & 7, src = key & 131071;
        int kk0 = rel * NN + src;
        float v = el_all[kk0 * 4 + h] + er_all[(rel * NN + d) * 4 + h];
        v = v > 0.f ? v : 0.2f * v;
        float w0 = __expf(v);
        uint4 u = *(const uint4*)&feat_all[kk0 * 64 + fl * 8];
        acc[0] += bflo(u.x) * w0;
        acc[1] += bfhi(u.x) * w0;
        acc[2] += bflo(u.y) * w0;
        acc[3] += bfhi(u.y) * w0;
        acc[4] += bflo(u.z) * w0;
        acc[5] += bfhi(u.z) * w0;
        acc[6] += bflo(u.w) * w0;
        acc[7] += bfhi(u.w) * w0;
        accW += w0;
    }

    {
        float invh = 1.f / fmaxf(accW, 1e-16f);
        float o[8];
#pragma unroll
        for (int q = 0; q < 8; ++q) o[q] = acc[q] * invh + bv[q];
        if (isf32) {
            ((f32x4*)out)[d * 16 + fl * 2]     = f32x4{o[0], o[1], o[2], o[3]};
            ((f32x4*)out)[d * 16 + fl * 2 + 1] = f32x4{o[4], o[5], o[6], o[7]};
        } else {
            uint4 st;
            st.x = (u32)f2bf(o[0]) | ((u32)f2bf(o[1]) << 16);
            st.y = (u32)f2bf(o[2]) | ((u32)f2bf(o[3]) << 16);
            st.z = (u32)f2bf(o[4]) | ((u32)f2bf(o[5]) << 16);
            st.w = (u32)f2bf(o[6]) | ((u32)f2bf(o[7]) << 16);
            *(uint4*)&((u16*)out)[d * 64 + fl * 8] = st;
        }
    }
}

extern "C" void kernel_launch(void* const* d_in, const int* in_sizes, int n_in,
                              void* d_out, int out_size, void* d_ws, size_t ws_size,
                              hipStream_t stream)
{
    const void* x   = d_in[0];
    const int* srci = (const int*)d_in[1];
    const int* dsti = (const int*)d_in[2];
    const int* reli = (const int*)d_in[3];
    const void* cw  = d_in[4];
    const void* al  = d_in[5];
    const void* ar  = d_in[6];
    const void* hb  = d_in[7];

    // workspace layout (bytes, 16B-aligned), ~137.3 MB used
    char* ws = (char*)d_ws;
    u16*   feat_all = (u16*)  (ws + 0);            // 102,400,000
    float* el_all   = (float*)(ws + 102400000);    //  12,800,000
    float* er_all   = (float*)(ws + 115200000);    //  12,800,000
    int*   key_s    = (int*)  (ws + 128000000);    //   4,000,000
    int*   key_b    = (int*)  (ws + 132000000);    //   4,000,000
    int*   off      = (int*)  (ws + 136000000);    //     400,064
    int*   histT    = (int*)  (ws + 136400064);    //     765,968
    int*   bsum     = (int*)  (ws + 137166032);    //       3,008
    int*   boff     = (int*)  (ws + 137169040);    //       3,008
    int*   bstart   = (int*)  (ws + 137172048);    //         832
    u16*   Bpre     = (u16*)  (ws + 137172880);    //      81,920
    int*   flag     = (int*)  (ws + 137254800);    //           4

    k_pre<<<PRE_BLKS, 256, 0, stream>>>(x, flag, cw, al, ar, Bpre, dsti, histT);
    k1_feat<<<K1B + NBB, 256, 0, stream>>>(x, Bpre, feat_all, el_all, er_all,
                                           histT, bsum);
    k_scanB2<<<1, 1024, 0, stream>>>(bsum, boff, histT, bstart);
    k_binC<<<NBLK, 256, 0, stream>>>(srci, dsti, reli, histT, boff, key_b);
    k_binD<<<NBUCK, 1024, 0, stream>>>(bstart, key_b, key_s, off);
    k3_node<<<(NN + 31) / 32, 256, 0, stream>>>(off, key_s, el_all, er_all, feat_all,
                                                hb, flag, d_out);
}